// Round 1
// baseline (502.516 us; speedup 1.0000x reference)
//
#include <hip/hip_runtime.h>

#define N_NODES 100000
#define N2_NODES 1800
#define ENC_NEGINF 0x007FFFFFu

__device__ __forceinline__ unsigned enc_f(float f) {
    unsigned u = __float_as_uint(f);
    return (u & 0x80000000u) ? ~u : (u | 0x80000000u);
}
__device__ __forceinline__ float dec_f(unsigned k) {
    return (k & 0x80000000u) ? __uint_as_float(k & 0x7fffffffu) : __uint_as_float(~k);
}

// ---------------- init: zero stats/cnt/pacc, set max-keys to enc(-inf) -------
__global__ void init_k(float* stats, unsigned* keys3, float* cnt, float* pacc,
                       unsigned* keys5) {
    int t = blockIdx.x * blockDim.x + threadIdx.x;   // 225*256 = 57600 threads
    if (t < 1280)  stats[t] = 0.f;
    if (t < 57600) keys3[t] = ENC_NEGINF;
    if (t < 1800)  cnt[t]   = 0.f;
    if (t < 5400)  pacc[t]  = 0.f;
    if (t < 16384) keys5[t] = ENC_NEGINF;
}

// ---------------- PassA: node transform (h | a_src | a_dst) ------------------
// MODE 0: f = in directly.  MODE 1: f = in*scale+shift (also writes z).
// MODE 2: f = in*scale+shift + skip.
template<int CIN, int COUT, int MODE>
__global__ void pass_a(const float* __restrict__ in, const float* __restrict__ scv,
                       const float* __restrict__ shv, const float* __restrict__ skip,
                       const float* __restrict__ wl, const float* __restrict__ wsrc,
                       const float* __restrict__ wdst, float* __restrict__ hsa,
                       float* __restrict__ zout) {
    int idx = blockIdx.x * blockDim.x + threadIdx.x;
    int i = idx / COUT, c = idx % COUT;
    float f[CIN];
#pragma unroll
    for (int r = 0; r < CIN; ++r) {
        float v = in[i * CIN + r];
        if (MODE >= 1) v = v * scv[r] + shv[r];
        if (MODE == 2) v += skip[i * CIN + r];
        f[r] = v;
    }
    float h = 0.f, as = 0.f, ad = 0.f;
#pragma unroll
    for (int r = 0; r < CIN; ++r) {
        h  += f[r] * wl[r * COUT + c];
        as += f[r] * wsrc[r * COUT + c];
        ad += f[r] * wdst[r * COUT + c];
    }
    hsa[i * 3 * COUT + c]            = h;
    hsa[i * 3 * COUT + COUT + c]     = as;
    hsa[i * 3 * COUT + 2 * COUT + c] = ad;
    if (MODE == 1 && c < CIN)   // recompute (avoid runtime-indexed reg array)
        zout[i * CIN + c] = in[i * CIN + c] * scv[c] + shv[c];
}

// ---------------- Edge pass: per-dst register softmax + aggregate -----------
// FINE: node i edges at [16i,16i+16) + self.  COARSE: b*1800 + k*225 + j + self.
template<int C, bool COARSE>
__global__ void edge_pass(const float* __restrict__ hsa, const float* __restrict__ pos,
                          const int* __restrict__ esrc, const float* __restrict__ wpos,
                          const float* __restrict__ bpos, float* __restrict__ y,
                          float* __restrict__ stats) {
    constexpr int NPB  = 256 / C;
    constexpr int DEG_ = COARSE ? 8 : 16;
    int tid = threadIdx.x;
    int c = tid % C;
    int i = blockIdx.x * NPB + tid / C;

    float wp0 = wpos[c], wp1 = wpos[C + c], wp2 = wpos[2 * C + c], bp = bpos[c];
    float px = pos[i * 3], py = pos[i * 3 + 1], pz = pos[i * 3 + 2];
    float adst = hsa[i * 3 * C + 2 * C + c];
    int b = 0, j = 0;
    if (COARSE) { b = i / 225; j = i % 225; }

    float alpha[DEG_ + 1], m[DEG_ + 1];
    float amax = -3.402823466e+38f;
#pragma unroll
    for (int e = 0; e <= DEG_; ++e) {
        int s;
        if (e < DEG_) s = COARSE ? esrc[b * 1800 + e * 225 + j] : esrc[i * 16 + e];
        else          s = i;
        float dx = px - pos[s * 3], dy = py - pos[s * 3 + 1], dz = pz - pos[s * 3 + 2];
        float delta = dx * wp0 + dy * wp1 + dz * wp2 + bp;
        alpha[e] = adst - hsa[s * 3 * C + C + c] + delta;
        m[e]     = hsa[s * 3 * C + c] + delta;
        amax = fmaxf(amax, alpha[e]);
    }
    float den = 0.f, acc = 0.f;
#pragma unroll
    for (int e = 0; e <= DEG_; ++e) {
        float ex = __expf(alpha[e] - amax);
        den += ex;
        acc += ex * m[e];
    }
    float out = acc / (den + 1e-16f);
    float yv = out > 0.f ? out : (__expf(out) - 1.f);
    y[i * C + c] = yv;

    __shared__ float ls[C], lq[C];
    if (tid < C) { ls[tid] = 0.f; lq[tid] = 0.f; }
    __syncthreads();
    atomicAdd(&ls[c], yv);
    atomicAdd(&lq[c], yv * yv);
    __syncthreads();
    if (tid < C) {
        atomicAdd(&stats[tid], ls[tid]);
        atomicAdd(&stats[128 + tid], lq[tid]);
    }
}

// ---------------- BN finalize: scale/shift per channel ----------------------
__global__ void bn_fin(const float* __restrict__ st, const float* __restrict__ g,
                       const float* __restrict__ be, float* __restrict__ ss,
                       int C, float invn) {
    int c = threadIdx.x;
    if (c >= C) return;
    float mu  = st[c] * invn;
    float var = fmaxf(st[128 + c] * invn - mu * mu, 0.f);
    float s = g[c] / sqrtf(var + 1e-5f);
    ss[c] = s;
    ss[128 + c] = be[c] - mu * s;
}

// ---------------- pool3: voxel max-pool + pos mean accumulation -------------
__global__ void pool3_k(const float* __restrict__ y3, const float* __restrict__ ss,
                        const float* __restrict__ pos, const int* __restrict__ batch,
                        unsigned* __restrict__ keys, float* __restrict__ cnt,
                        float* __restrict__ pacc) {
    int tid = threadIdx.x;
    int c = tid % 32;
    int i = blockIdx.x * 8 + tid / 32;
    float z = y3[i * 32 + c] * ss[c] + ss[128 + c];
    float px = pos[i * 3], py = pos[i * 3 + 1];
    int cx = min(max((int)floorf(px / 16.f), 0), 14);
    int cy = min(max((int)floorf(py / 12.f), 0), 14);
    int cl = batch[i] * 225 + cy * 15 + cx;
    atomicMax(&keys[cl * 32 + c], enc_f(z));
    if (c == 0) {
        atomicAdd(&cnt[cl], 1.f);
        atomicAdd(&pacc[cl * 3 + 0], px);
        atomicAdd(&pacc[cl * 3 + 1], py);
        atomicAdd(&pacc[cl * 3 + 2], pos[i * 3 + 2]);
    }
}

__global__ void pool3_fin(const unsigned* __restrict__ keys, const float* __restrict__ cnt,
                          const float* __restrict__ pacc, float* __restrict__ x2,
                          float* __restrict__ pos2) {
    int idx = blockIdx.x * blockDim.x + threadIdx.x;   // 1800*32
    int cl = idx / 32, c = idx % 32;
    unsigned k = keys[idx];
    x2[idx] = (k == ENC_NEGINF) ? 0.f : dec_f(k);
    if (c < 3) pos2[cl * 3 + c] = pacc[cl * 3 + c] / fmaxf(cnt[cl], 1.f);
}

// ---------------- pool5: 4x4 grid max over pooled nodes ---------------------
__global__ void pool5_k(const float* __restrict__ y5, const float* __restrict__ ss,
                        const float* __restrict__ pos2, unsigned* __restrict__ keys5) {
    int idx = blockIdx.x * blockDim.x + threadIdx.x;   // 1800*128
    int i = idx / 128, c = idx % 128;
    float z = y5[idx] * ss[c] + ss[128 + c];
    float px = pos2[i * 3], py = pos2[i * 3 + 1];
    int cx = min(max((int)floorf(px / 60.f), 0), 3);
    int cy = min(max((int)floorf(py / 45.f), 0), 3);
    int b = i / 225;
    int cl = b * 16 + cy * 4 + cx;
    atomicMax(&keys5[cl * 128 + c], enc_f(z));
}

// ---------------- FC: (8,2048) @ (2048,101) ----------------------------------
__global__ void fc_k(const unsigned* __restrict__ keys5, const float* __restrict__ wfc,
                     float* __restrict__ out) {
    __shared__ float row[2048];
    int b = blockIdx.x;
    for (int k = threadIdx.x; k < 2048; k += blockDim.x) {
        unsigned kk = keys5[b * 2048 + k];
        row[k] = (kk == ENC_NEGINF) ? 0.f : dec_f(kk);
    }
    __syncthreads();
    int o = threadIdx.x;
    if (o < 101) {
        float a0 = 0.f, a1 = 0.f, a2 = 0.f, a3 = 0.f;
        for (int k = 0; k < 2048; k += 4) {
            a0 += row[k]     * wfc[k * 101 + o];
            a1 += row[k + 1] * wfc[(k + 1) * 101 + o];
            a2 += row[k + 2] * wfc[(k + 2) * 101 + o];
            a3 += row[k + 3] * wfc[(k + 3) * 101 + o];
        }
        out[b * 101 + o] = (a0 + a1) + (a2 + a3);
    }
}

extern "C" void kernel_launch(void* const* d_in, const int* in_sizes, int n_in,
                              void* d_out, int out_size, void* d_ws, size_t ws_size,
                              hipStream_t stream) {
    const float* x     = (const float*)d_in[0];
    const float* pos   = (const float*)d_in[1];
    const int*   batch = (const int*)d_in[2];
    const int*   e1    = (const int*)d_in[3];   // src = first E entries
    const int*   e2    = (const int*)d_in[4];   // src = first 14400 entries
    const float* w_fc  = (const float*)d_in[40];
    auto WL = [&](int l) { return (const float*)d_in[5 + l * 7 + 0]; };
    auto WS = [&](int l) { return (const float*)d_in[5 + l * 7 + 1]; };
    auto WD = [&](int l) { return (const float*)d_in[5 + l * 7 + 2]; };
    auto WP = [&](int l) { return (const float*)d_in[5 + l * 7 + 3]; };
    auto BP = [&](int l) { return (const float*)d_in[5 + l * 7 + 4]; };
    auto G_ = [&](int l) { return (const float*)d_in[5 + l * 7 + 5]; };
    auto BE = [&](int l) { return (const float*)d_in[5 + l * 7 + 6]; };

    float* W = (float*)d_ws;
    size_t o = 0;
    float* HSA = W;            o += 9600000;  // N * 96 (reused L1..L3)
    float* Y1  = W + o;        o += 800000;
    float* Y2  = W + o;        o += 800000;
    float* Z1  = W + o;        o += 800000;
    float* Y3  = W + o;        o += 3200000;
    float* STATS = W + o;      o += 5 * 256;  // per layer: sum@+0, sumsq@+128
    float* SS    = W + o;      o += 5 * 256;  // per layer: scale@+0, shift@+128
    unsigned* KEYS3 = (unsigned*)(W + o); o += 57600;
    float* CNT  = W + o;       o += 1800;
    float* PACC = W + o;       o += 5400;
    float* X2   = W + o;       o += 57600;
    float* POS2 = W + o;       o += 5400;
    float* HSAC = W + o;       o += 691200;   // 1800 * 384 (reused L4,L5)
    float* Y4   = W + o;       o += 57600;
    float* Y5   = W + o;       o += 230400;
    unsigned* KEYS5 = (unsigned*)(W + o); o += 16384;

    const float invN  = 1.0f / (float)N_NODES;
    const float invN2 = 1.0f / (float)N2_NODES;

    hipLaunchKernelGGL(init_k, dim3(225), dim3(256), 0, stream,
                       STATS, KEYS3, CNT, PACC, KEYS5);

    // ---- Layer 1 (1 -> 8), fine graph ----
    hipLaunchKernelGGL((pass_a<1, 8, 0>), dim3(3125), dim3(256), 0, stream,
                       x, nullptr, nullptr, nullptr, WL(0), WS(0), WD(0), HSA, nullptr);
    hipLaunchKernelGGL((edge_pass<8, false>), dim3(3125), dim3(256), 0, stream,
                       HSA, pos, e1, WP(0), BP(0), Y1, STATS + 0);
    hipLaunchKernelGGL(bn_fin, dim3(1), dim3(128), 0, stream,
                       STATS + 0, G_(0), BE(0), SS + 0, 8, invN);

    // ---- Layer 2 (8 -> 8), fine graph, writes Z1 = bn(y1) for residual ----
    hipLaunchKernelGGL((pass_a<8, 8, 1>), dim3(3125), dim3(256), 0, stream,
                       Y1, SS + 0, SS + 128, nullptr, WL(1), WS(1), WD(1), HSA, Z1);
    hipLaunchKernelGGL((edge_pass<8, false>), dim3(3125), dim3(256), 0, stream,
                       HSA, pos, e1, WP(1), BP(1), Y2, STATS + 256);
    hipLaunchKernelGGL(bn_fin, dim3(1), dim3(128), 0, stream,
                       STATS + 256, G_(1), BE(1), SS + 256, 8, invN);

    // ---- Layer 3 (8 -> 32), fine graph, input = bn(y2) + Z1 ----
    hipLaunchKernelGGL((pass_a<8, 32, 2>), dim3(12500), dim3(256), 0, stream,
                       Y2, SS + 256, SS + 256 + 128, Z1, WL(2), WS(2), WD(2), HSA, nullptr);
    hipLaunchKernelGGL((edge_pass<32, false>), dim3(12500), dim3(256), 0, stream,
                       HSA, pos, e1, WP(2), BP(2), Y3, STATS + 512);
    hipLaunchKernelGGL(bn_fin, dim3(1), dim3(128), 0, stream,
                       STATS + 512, G_(2), BE(2), SS + 512, 32, invN);

    // ---- pool3: z3 = bn(y3) -> voxel max, pos mean ----
    hipLaunchKernelGGL(pool3_k, dim3(12500), dim3(256), 0, stream,
                       Y3, SS + 512, pos, batch, KEYS3, CNT, PACC);
    hipLaunchKernelGGL(pool3_fin, dim3(225), dim3(256), 0, stream,
                       KEYS3, CNT, PACC, X2, POS2);

    // ---- Layer 4 (32 -> 32), coarse graph, input = X2 ----
    hipLaunchKernelGGL((pass_a<32, 32, 0>), dim3(225), dim3(256), 0, stream,
                       X2, nullptr, nullptr, nullptr, WL(3), WS(3), WD(3), HSAC, nullptr);
    hipLaunchKernelGGL((edge_pass<32, true>), dim3(225), dim3(256), 0, stream,
                       HSAC, POS2, e2, WP(3), BP(3), Y4, STATS + 768);
    hipLaunchKernelGGL(bn_fin, dim3(1), dim3(128), 0, stream,
                       STATS + 768, G_(3), BE(3), SS + 768, 32, invN2);

    // ---- Layer 5 (32 -> 128), coarse graph, input = bn(y4) + X2 ----
    hipLaunchKernelGGL((pass_a<32, 128, 2>), dim3(900), dim3(256), 0, stream,
                       Y4, SS + 768, SS + 768 + 128, X2, WL(4), WS(4), WD(4), HSAC, nullptr);
    hipLaunchKernelGGL((edge_pass<128, true>), dim3(900), dim3(256), 0, stream,
                       HSAC, POS2, e2, WP(4), BP(4), Y5, STATS + 1024);
    hipLaunchKernelGGL(bn_fin, dim3(1), dim3(128), 0, stream,
                       STATS + 1024, G_(4), BE(4), SS + 1024, 128, invN2);

    // ---- pool5 + FC ----
    hipLaunchKernelGGL(pool5_k, dim3(900), dim3(256), 0, stream,
                       Y5, SS + 1024, POS2, KEYS5);
    hipLaunchKernelGGL(fc_k, dim3(8), dim3(128), 0, stream,
                       KEYS5, w_fc, (float*)d_out);
}

// Round 2
// 444.586 us; speedup vs baseline: 1.1303x; 1.1303x over previous
//
#include <hip/hip_runtime.h>

#define ENC_NEGINF 0x007FFFFFu
#define INV_N  (1.0f / 100000.0f)
#define INV_N2 (1.0f / 1800.0f)

__device__ __forceinline__ unsigned enc_f(float f) {
    unsigned u = __float_as_uint(f);
    return (u & 0x80000000u) ? ~u : (u | 0x80000000u);
}
__device__ __forceinline__ float dec_f(unsigned k) {
    return (k & 0x80000000u) ? __uint_as_float(k & 0x7fffffffu) : __uint_as_float(~k);
}

// bijective XCD-aware swizzle (m204 variant)
__device__ __forceinline__ int xcd_swz(int bid, int nwg) {
    int q = nwg >> 3, r = nwg & 7;
    int xcd = bid & 7, idx = bid >> 3;
    return (xcd < r ? xcd * (q + 1) : r * (q + 1) + (xcd - r) * q) + idx;
}

// per-channel BN scale/shift from raw stats
__device__ __forceinline__ float2 bn_ss(const float* __restrict__ st,
                                        const float* __restrict__ g,
                                        const float* __restrict__ be,
                                        int r, float invn) {
    float mu  = st[r] * invn;
    float var = fmaxf(st[128 + r] * invn - mu * mu, 0.f);
    float s = g[r] * rsqrtf(var + 1e-5f);
    return make_float2(s, be[r] - mu * s);
}

// ---------------- init: zero stats/cnt/pacc, set max-keys to enc(-inf) ------
__global__ void init_k(float* stats, unsigned* keys3, float* cnt, float* pacc,
                       unsigned* keys5) {
    int t = blockIdx.x * blockDim.x + threadIdx.x;   // 225*256 = 57600 threads
    if (t < 1280)  stats[t] = 0.f;
    if (t < 57600) keys3[t] = ENC_NEGINF;
    if (t < 1800)  cnt[t]   = 0.f;
    if (t < 5400)  pacc[t]  = 0.f;
    if (t < 16384) keys5[t] = ENC_NEGINF;
}

// ---------------- PassA: node transform -> SH=(a_src+Pd, h-Pd), CA=Pd+bp ----
// MODE 0: f = in.  MODE 1: f = bn(in) (also writes z=bn(in)).  MODE 2: bn(in)+skip.
template<int CIN, int COUT, int MODE>
__global__ void pass_a(const float* __restrict__ in, const float* __restrict__ st,
                       const float* __restrict__ g, const float* __restrict__ be,
                       float invn, const float* __restrict__ skip,
                       const float* __restrict__ wl, const float* __restrict__ wsrc,
                       const float* __restrict__ wpos, const float* __restrict__ bpos,
                       const float* __restrict__ pos,
                       float2* __restrict__ SH, float* __restrict__ CA,
                       float* __restrict__ zout) {
    int idx = blockIdx.x * blockDim.x + threadIdx.x;
    int i = idx / COUT, c = idx % COUT;
    float f[CIN];
#pragma unroll
    for (int r = 0; r < CIN; ++r) {
        float v = in[i * CIN + r];
        if constexpr (MODE >= 1) {
            float2 ss = bn_ss(st, g, be, r, invn);
            v = v * ss.x + ss.y;
        }
        if constexpr (MODE == 2) v += skip[i * CIN + r];
        f[r] = v;
    }
    float h = 0.f, a = 0.f;
#pragma unroll
    for (int r = 0; r < CIN; ++r) {
        h += f[r] * wl[r * COUT + c];
        a += f[r] * wsrc[r * COUT + c];
    }
    float pd = pos[i * 3] * wpos[c] + pos[i * 3 + 1] * wpos[COUT + c]
             + pos[i * 3 + 2] * wpos[2 * COUT + c];
    SH[i * COUT + c] = make_float2(a + pd, h - pd);
    CA[i * COUT + c] = pd + bpos[c];
    if constexpr (MODE == 1) {
        if (c < CIN) {
            float2 ss = bn_ss(st, g, be, c, invn);
            zout[i * CIN + c] = in[i * CIN + c] * ss.x + ss.y;
        }
    }
}

// ---------------- Edge pass: 1 float2 gather per edge, register softmax -----
template<int C, bool COARSE>
__global__ void edge_pass(const float2* __restrict__ SH, const float* __restrict__ CA,
                          const int* __restrict__ esrc, float* __restrict__ y,
                          float* __restrict__ stats) {
    constexpr int NPB  = 256 / C;
    constexpr int DEG_ = COARSE ? 8 : 16;
    int bid = COARSE ? (int)blockIdx.x : xcd_swz(blockIdx.x, gridDim.x);
    int tid = threadIdx.x;
    int c = tid % C;
    int i = bid * NPB + tid / C;

    int sidx[DEG_ + 1];
    if constexpr (!COARSE) {
        const int4* e4 = reinterpret_cast<const int4*>(esrc + i * 16);
        int4 q0 = e4[0], q1 = e4[1], q2 = e4[2], q3 = e4[3];
        sidx[0] = q0.x; sidx[1] = q0.y; sidx[2]  = q0.z; sidx[3]  = q0.w;
        sidx[4] = q1.x; sidx[5] = q1.y; sidx[6]  = q1.z; sidx[7]  = q1.w;
        sidx[8] = q2.x; sidx[9] = q2.y; sidx[10] = q2.z; sidx[11] = q2.w;
        sidx[12] = q3.x; sidx[13] = q3.y; sidx[14] = q3.z; sidx[15] = q3.w;
    } else {
        int b = i / 225, j = i % 225;
#pragma unroll
        for (int e = 0; e < DEG_; ++e) sidx[e] = esrc[b * 1800 + e * 225 + j];
    }
    sidx[DEG_] = i;

    float S[DEG_ + 1], Hv[DEG_ + 1];
#pragma unroll
    for (int e = 0; e <= DEG_; ++e) {
        float2 sh = SH[sidx[e] * C + c];
        S[e] = sh.x; Hv[e] = sh.y;
    }
    float smin = S[0];
#pragma unroll
    for (int e = 1; e <= DEG_; ++e) smin = fminf(smin, S[e]);
    float den = 0.f, acc = 0.f;
#pragma unroll
    for (int e = 0; e <= DEG_; ++e) {
        float ex = __expf(smin - S[e]);
        den += ex;
        acc += ex * Hv[e];
    }
    float Ci = CA[i * C + c];
    float out = (acc + Ci * den) / (den + 1e-16f);
    float yv = out > 0.f ? out : (__expf(out) - 1.f);
    y[i * C + c] = yv;

    // BN stats: shfl-reduce within wave (same c lanes), then LDS, then global
    float s1 = yv, s2 = yv * yv;
    if constexpr (C <= 32) {
#pragma unroll
        for (int m = C; m < 64; m <<= 1) {
            s1 += __shfl_xor(s1, m);
            s2 += __shfl_xor(s2, m);
        }
    }
    __shared__ float ls[C], lq[C];
    if (tid < C) { ls[tid] = 0.f; lq[tid] = 0.f; }
    __syncthreads();
    bool doadd = (C > 32) || ((tid & 63) < C);
    if (doadd) { atomicAdd(&ls[c], s1); atomicAdd(&lq[c], s2); }
    __syncthreads();
    if (tid < C) {
        atomicAdd(&stats[tid], ls[tid]);
        atomicAdd(&stats[128 + tid], lq[tid]);
    }
}

// ---------------- pool3: voxel max-pool + pos mean accumulation -------------
__global__ void pool3_k(const float* __restrict__ y3, const float* __restrict__ st,
                        const float* __restrict__ g, const float* __restrict__ be,
                        const float* __restrict__ pos, const int* __restrict__ batch,
                        unsigned* __restrict__ keys, float* __restrict__ cnt,
                        float* __restrict__ pacc) {
    int tid = threadIdx.x;
    int c = tid & 31;
    int i = blockIdx.x * 8 + (tid >> 5);
    float2 ss = bn_ss(st, g, be, c, INV_N);
    float z = y3[i * 32 + c] * ss.x + ss.y;
    float px = pos[i * 3], py = pos[i * 3 + 1];
    int cx = min(max((int)floorf(px / 16.f), 0), 14);
    int cy = min(max((int)floorf(py / 12.f), 0), 14);
    int cl = batch[i] * 225 + cy * 15 + cx;
    atomicMax(&keys[cl * 32 + c], enc_f(z));
    if (c == 0) {
        atomicAdd(&cnt[cl], 1.f);
        atomicAdd(&pacc[cl * 3 + 0], px);
        atomicAdd(&pacc[cl * 3 + 1], py);
        atomicAdd(&pacc[cl * 3 + 2], pos[i * 3 + 2]);
    }
}

__global__ void pool3_fin(const unsigned* __restrict__ keys, const float* __restrict__ cnt,
                          const float* __restrict__ pacc, float* __restrict__ x2,
                          float* __restrict__ pos2) {
    int idx = blockIdx.x * blockDim.x + threadIdx.x;   // 1800*32
    int cl = idx / 32, c = idx % 32;
    unsigned k = keys[idx];
    x2[idx] = (k == ENC_NEGINF) ? 0.f : dec_f(k);
    if (c < 3) pos2[cl * 3 + c] = pacc[cl * 3 + c] / fmaxf(cnt[cl], 1.f);
}

// ---------------- pool5: 4x4 grid max over pooled nodes ---------------------
__global__ void pool5_k(const float* __restrict__ y5, const float* __restrict__ st,
                        const float* __restrict__ g, const float* __restrict__ be,
                        const float* __restrict__ pos2, unsigned* __restrict__ keys5) {
    int idx = blockIdx.x * blockDim.x + threadIdx.x;   // 1800*128
    int i = idx / 128, c = idx % 128;
    float2 ss = bn_ss(st, g, be, c, INV_N2);
    float z = y5[idx] * ss.x + ss.y;
    float px = pos2[i * 3], py = pos2[i * 3 + 1];
    int cx = min(max((int)floorf(px / 60.f), 0), 3);
    int cy = min(max((int)floorf(py / 45.f), 0), 3);
    int b = i / 225;
    int cl = b * 16 + cy * 4 + cx;
    atomicMax(&keys5[cl * 128 + c], enc_f(z));
}

// ---------------- FC: (8,2048) @ (2048,101), one wave per output ------------
__global__ void fc_k(const unsigned* __restrict__ keys5, const float* __restrict__ wfc,
                     float* __restrict__ out) {
    __shared__ float row[2048];
    int b = blockIdx.x;
    for (int k = threadIdx.x; k < 2048; k += 256) {
        unsigned kk = keys5[b * 2048 + k];
        row[k] = (kk == ENC_NEGINF) ? 0.f : dec_f(kk);
    }
    __syncthreads();
    int wave = threadIdx.x >> 6, lane = threadIdx.x & 63;
    int o = blockIdx.y * 4 + wave;
    if (o < 101) {
        float a = 0.f;
        for (int k = lane; k < 2048; k += 64)
            a += row[k] * wfc[k * 101 + o];
#pragma unroll
        for (int m = 32; m; m >>= 1) a += __shfl_xor(a, m);
        if (lane == 0) out[b * 101 + o] = a;
    }
}

extern "C" void kernel_launch(void* const* d_in, const int* in_sizes, int n_in,
                              void* d_out, int out_size, void* d_ws, size_t ws_size,
                              hipStream_t stream) {
    const float* x     = (const float*)d_in[0];
    const float* pos   = (const float*)d_in[1];
    const int*   batch = (const int*)d_in[2];
    const int*   e1    = (const int*)d_in[3];   // src = first E entries
    const int*   e2    = (const int*)d_in[4];   // src = first 14400 entries
    const float* w_fc  = (const float*)d_in[40];
    auto WL = [&](int l) { return (const float*)d_in[5 + l * 7 + 0]; };
    auto WS = [&](int l) { return (const float*)d_in[5 + l * 7 + 1]; };
    auto WP = [&](int l) { return (const float*)d_in[5 + l * 7 + 3]; };
    auto BP = [&](int l) { return (const float*)d_in[5 + l * 7 + 4]; };
    auto G_ = [&](int l) { return (const float*)d_in[5 + l * 7 + 5]; };
    auto BE = [&](int l) { return (const float*)d_in[5 + l * 7 + 6]; };

    float* W = (float*)d_ws;
    size_t o = 0;
    float2* SHf = (float2*)W;      o += 6400000;   // N*32 float2 (reused L1..L3)
    float*  CAf = W + o;           o += 3200000;   // N*32
    float*  Y1  = W + o;           o += 800000;
    float*  Y2  = W + o;           o += 800000;
    float*  Z1  = W + o;           o += 800000;
    float*  Y3  = W + o;           o += 3200000;
    float*  STATS = W + o;         o += 5 * 256;   // per layer: sum@+0, sumsq@+128
    unsigned* KEYS3 = (unsigned*)(W + o); o += 57600;
    float*  CNT  = W + o;          o += 1800;
    float*  PACC = W + o;          o += 5400;
    float*  X2   = W + o;          o += 57600;
    float*  POS2 = W + o;          o += 5400;
    float2* SHc  = (float2*)(W + o); o += 460800;  // 1800*128 float2 (L4,L5)
    float*  CAc  = W + o;          o += 230400;
    float*  Y4   = W + o;          o += 57600;
    float*  Y5   = W + o;          o += 230400;
    unsigned* KEYS5 = (unsigned*)(W + o); o += 16384;

    hipLaunchKernelGGL(init_k, dim3(225), dim3(256), 0, stream,
                       STATS, KEYS3, CNT, PACC, KEYS5);

    // ---- Layer 1 (1 -> 8), fine ----
    hipLaunchKernelGGL((pass_a<1, 8, 0>), dim3(3125), dim3(256), 0, stream,
                       x, nullptr, nullptr, nullptr, 0.f, nullptr,
                       WL(0), WS(0), WP(0), BP(0), pos, SHf, CAf, nullptr);
    hipLaunchKernelGGL((edge_pass<8, false>), dim3(3125), dim3(256), 0, stream,
                       SHf, CAf, e1, Y1, STATS + 0);

    // ---- Layer 2 (8 -> 8), fine; also writes Z1 = bn(Y1) ----
    hipLaunchKernelGGL((pass_a<8, 8, 1>), dim3(3125), dim3(256), 0, stream,
                       Y1, STATS + 0, G_(0), BE(0), INV_N, nullptr,
                       WL(1), WS(1), WP(1), BP(1), pos, SHf, CAf, Z1);
    hipLaunchKernelGGL((edge_pass<8, false>), dim3(3125), dim3(256), 0, stream,
                       SHf, CAf, e1, Y2, STATS + 256);

    // ---- Layer 3 (8 -> 32), fine; input = bn(Y2) + Z1 ----
    hipLaunchKernelGGL((pass_a<8, 32, 2>), dim3(12500), dim3(256), 0, stream,
                       Y2, STATS + 256, G_(1), BE(1), INV_N, Z1,
                       WL(2), WS(2), WP(2), BP(2), pos, SHf, CAf, nullptr);
    hipLaunchKernelGGL((edge_pass<32, false>), dim3(12500), dim3(256), 0, stream,
                       SHf, CAf, e1, Y3, STATS + 512);

    // ---- pool3: bn(Y3) -> voxel max, pos mean ----
    hipLaunchKernelGGL(pool3_k, dim3(12500), dim3(256), 0, stream,
                       Y3, STATS + 512, G_(2), BE(2), pos, batch, KEYS3, CNT, PACC);
    hipLaunchKernelGGL(pool3_fin, dim3(225), dim3(256), 0, stream,
                       KEYS3, CNT, PACC, X2, POS2);

    // ---- Layer 4 (32 -> 32), coarse ----
    hipLaunchKernelGGL((pass_a<32, 32, 0>), dim3(225), dim3(256), 0, stream,
                       X2, nullptr, nullptr, nullptr, 0.f, nullptr,
                       WL(3), WS(3), WP(3), BP(3), POS2, SHc, CAc, nullptr);
    hipLaunchKernelGGL((edge_pass<32, true>), dim3(225), dim3(256), 0, stream,
                       SHc, CAc, e2, Y4, STATS + 768);

    // ---- Layer 5 (32 -> 128), coarse; input = bn(Y4) + X2 ----
    hipLaunchKernelGGL((pass_a<32, 128, 2>), dim3(900), dim3(256), 0, stream,
                       Y4, STATS + 768, G_(3), BE(3), INV_N2, X2,
                       WL(4), WS(4), WP(4), BP(4), POS2, SHc, CAc, nullptr);
    hipLaunchKernelGGL((edge_pass<128, true>), dim3(900), dim3(256), 0, stream,
                       SHc, CAc, e2, Y5, STATS + 1024);

    // ---- pool5 + FC ----
    hipLaunchKernelGGL(pool5_k, dim3(900), dim3(256), 0, stream,
                       Y5, STATS + 1024, G_(4), BE(4), POS2, KEYS5);
    hipLaunchKernelGGL(fc_k, dim3(8, 26), dim3(256), 0, stream,
                       KEYS5, w_fc, (float*)d_out);
}

// Round 3
// 308.525 us; speedup vs baseline: 1.6288x; 1.4410x over previous
//
#include <hip/hip_runtime.h>

#define ENC_NEGINF 0x007FFFFFu
#define NN_FINE 100000
#define NN_COARSE 1800
#define INV_N  (1.0f / 100000.0f)
#define INV_N2 (1.0f / 1800.0f)

__device__ __forceinline__ unsigned enc_f(float f) {
    unsigned u = __float_as_uint(f);
    return (u & 0x80000000u) ? ~u : (u | 0x80000000u);
}
__device__ __forceinline__ float dec_f(unsigned k) {
    return (k & 0x80000000u) ? __uint_as_float(k & 0x7fffffffu) : __uint_as_float(~k);
}

// bijective XCD-aware swizzle (m204 variant)
__device__ __forceinline__ int xcd_swz(int bid, int nwg) {
    int q = nwg >> 3, r = nwg & 7;
    int xcd = bid & 7, idx = bid >> 3;
    return (xcd < r ? xcd * (q + 1) : r * (q + 1) + (xcd - r) * q) + idx;
}

__device__ __forceinline__ float2 bn_ss(const float* __restrict__ st,
                                        const float* __restrict__ g,
                                        const float* __restrict__ be,
                                        int r, float invn) {
    float mu  = st[r] * invn;
    float var = fmaxf(st[128 + r] * invn - mu * mu, 0.f);
    float s = g[r] * rsqrtf(var + 1e-5f);
    return make_float2(s, be[r] - mu * s);
}

// ---------------- init ------------------------------------------------------
__global__ void init_k(float* stats, unsigned* keys3, float* cnt, float* pacc,
                       unsigned* keys5) {
    int t = blockIdx.x * blockDim.x + threadIdx.x;   // 225*256 = 57600
    if (t < 1280)  stats[t] = 0.f;
    if (t < 57600) keys3[t] = ENC_NEGINF;
    if (t < 1800)  cnt[t]   = 0.f;
    if (t < 5400)  pacc[t]  = 0.f;
    if (t < 16384) keys5[t] = ENC_NEGINF;
}

// ---------------- PassA: per (node, channel-pair) ---------------------------
// MODE 0: f=in. 1: f=bn(in), write zout=bn(in). 2: f=bn(in)+skipf.
// 3: f=dec(keys). 4: f=bn(in)+dec(keys).
template<int CIN, int COUT, int MODE, bool CPOS>
__global__ void pass_a(const float* __restrict__ in, const unsigned* __restrict__ keys,
                       const float* __restrict__ st, const float* __restrict__ g,
                       const float* __restrict__ be, float invn,
                       const float* __restrict__ skipf,
                       const float* __restrict__ wl, const float* __restrict__ wsrc,
                       const float* __restrict__ wpos, const float* __restrict__ bpos,
                       const float* __restrict__ pos, const float* __restrict__ pacc,
                       const float* __restrict__ cnt,
                       float4* __restrict__ SHP, float2* __restrict__ CAP,
                       float* __restrict__ zout, int NN) {
    constexpr int P = COUT / 2;
    int idx = blockIdx.x * blockDim.x + threadIdx.x;
    int i = idx / P, p = idx % P;
    if (i >= NN) return;
    float f[CIN];
#pragma unroll
    for (int r = 0; r < CIN; ++r) {
        float v;
        if constexpr (MODE == 3) {
            v = 0.f;
        } else {
            v = in[i * CIN + r];
            if constexpr (MODE >= 1) {
                float2 ss = bn_ss(st, g, be, r, invn);
                v = v * ss.x + ss.y;
            }
            if constexpr (MODE == 2) v += skipf[i * CIN + r];
        }
        if constexpr (MODE == 3 || MODE == 4) {
            unsigned k = keys[i * CIN + r];
            v += (k == ENC_NEGINF) ? 0.f : dec_f(k);
        }
        f[r] = v;
    }
    int c0 = 2 * p;
    float h0 = 0.f, a0 = 0.f, h1 = 0.f, a1 = 0.f;
#pragma unroll
    for (int r = 0; r < CIN; ++r) {
        float2 wlr = *reinterpret_cast<const float2*>(&wl[r * COUT + c0]);
        float2 wsr = *reinterpret_cast<const float2*>(&wsrc[r * COUT + c0]);
        h0 += f[r] * wlr.x; h1 += f[r] * wlr.y;
        a0 += f[r] * wsr.x; a1 += f[r] * wsr.y;
    }
    float px, py, pz;
    if constexpr (CPOS) {
        float ic = 1.f / fmaxf(cnt[i], 1.f);
        px = pacc[i * 3] * ic; py = pacc[i * 3 + 1] * ic; pz = pacc[i * 3 + 2] * ic;
    } else {
        px = pos[i * 3]; py = pos[i * 3 + 1]; pz = pos[i * 3 + 2];
    }
    float2 w0 = *reinterpret_cast<const float2*>(&wpos[c0]);
    float2 w1 = *reinterpret_cast<const float2*>(&wpos[COUT + c0]);
    float2 w2 = *reinterpret_cast<const float2*>(&wpos[2 * COUT + c0]);
    float pd0 = px * w0.x + py * w1.x + pz * w2.x;
    float pd1 = px * w0.y + py * w1.y + pz * w2.y;
    float2 bp = *reinterpret_cast<const float2*>(&bpos[c0]);
    SHP[i * P + p] = make_float4(a0 + pd0, a1 + pd1, h0 - pd0, h1 - pd1);
    CAP[i * P + p] = make_float2(pd0 + bp.x, pd1 + bp.y);
    if constexpr (MODE == 1) {
        // CIN == COUT: recompute bn for channels c0, c0+1
        float2 s0 = bn_ss(st, g, be, c0, invn);
        float2 s1 = bn_ss(st, g, be, c0 + 1, invn);
        float2 zv = make_float2(in[i * CIN + c0] * s0.x + s0.y,
                                in[i * CIN + c0 + 1] * s1.x + s1.y);
        *reinterpret_cast<float2*>(&zout[i * CIN + c0]) = zv;
    }
}

// ---------------- Edge pass: 1 float4 gather per edge, no atomics -----------
template<int C, bool COARSE>
__global__ __launch_bounds__(256, 4)
void edge_pass(const float4* __restrict__ SHP, const float2* __restrict__ CAP,
               const int* __restrict__ esrc, float2* __restrict__ y2, int NN) {
    constexpr int P = C / 2;
    constexpr int NPB = 256 / P;
    constexpr int DEG_ = COARSE ? 8 : 16;
    __shared__ int se[NPB * DEG_];
    int bid = COARSE ? (int)blockIdx.x : xcd_swz(blockIdx.x, gridDim.x);
    int tid = threadIdx.x;
    int node0 = bid * NPB;
    if constexpr (!COARSE) {
        for (int t = tid; t < NPB * DEG_; t += 256)
            se[t] = esrc[node0 * 16 + t];          // in-bounds: dst half follows src
    } else {
        for (int t = tid; t < NPB * DEG_; t += 256) {
            int n = t / DEG_, e = t % DEG_;
            int i2 = node0 + n;
            if (i2 < NN) {
                int b = i2 / 225, j = i2 % 225;
                se[t] = esrc[b * 1800 + e * 225 + j];
            }
        }
    }
    __syncthreads();
    int n = tid / P, p = tid % P;
    int i = node0 + n;
    if (i >= NN) return;

    float4 q[DEG_ + 1];
#pragma unroll
    for (int e = 0; e < DEG_; ++e)
        q[e] = SHP[(size_t)se[n * DEG_ + e] * P + p];
    q[DEG_] = SHP[(size_t)i * P + p];

    float smin0 = q[0].x, smin1 = q[0].y;
#pragma unroll
    for (int e = 1; e <= DEG_; ++e) {
        smin0 = fminf(smin0, q[e].x);
        smin1 = fminf(smin1, q[e].y);
    }
    float den0 = 0.f, acc0 = 0.f, den1 = 0.f, acc1 = 0.f;
#pragma unroll
    for (int e = 0; e <= DEG_; ++e) {
        float ex0 = __expf(smin0 - q[e].x);
        float ex1 = __expf(smin1 - q[e].y);
        den0 += ex0; acc0 += ex0 * q[e].z;
        den1 += ex1; acc1 += ex1 * q[e].w;
    }
    float2 Ci = CAP[(size_t)i * P + p];
    float o0 = (acc0 + Ci.x * den0) / (den0 + 1e-16f);
    float o1 = (acc1 + Ci.y * den1) / (den1 + 1e-16f);
    float y0 = o0 > 0.f ? o0 : (__expf(o0) - 1.f);
    float y1 = o1 > 0.f ? o1 : (__expf(o1) - 1.f);
    y2[(size_t)i * P + p] = make_float2(y0, y1);
}

// ---------------- BN stats over y -------------------------------------------
template<int C>
__global__ void stats_k(const float* __restrict__ y, int total,
                        float* __restrict__ stats) {
    __shared__ float ls[C], lq[C];
    int tid = threadIdx.x;
    if (tid < C) { ls[tid] = 0.f; lq[tid] = 0.f; }
    __syncthreads();
    float s1 = 0.f, s2 = 0.f;
    int stride = gridDim.x * 256;
    int c = tid % C;   // stride and block offset are multiples of C
    for (int k = blockIdx.x * 256 + tid; k < total; k += stride) {
        float v = y[k];
        s1 += v; s2 += v * v;
    }
    if constexpr (C <= 32) {
#pragma unroll
        for (int m = C; m < 64; m <<= 1) {
            s1 += __shfl_xor(s1, m);
            s2 += __shfl_xor(s2, m);
        }
        if ((tid & 63) < C) { atomicAdd(&ls[c], s1); atomicAdd(&lq[c], s2); }
    } else {
        atomicAdd(&ls[c], s1); atomicAdd(&lq[c], s2);
    }
    __syncthreads();
    if (tid < C) {
        atomicAdd(&stats[tid], ls[tid]);
        atomicAdd(&stats[128 + tid], lq[tid]);
    }
}

// ---------------- pool3 -----------------------------------------------------
__global__ void pool3_k(const float* __restrict__ y3, const float* __restrict__ st,
                        const float* __restrict__ g, const float* __restrict__ be,
                        const float* __restrict__ pos, const int* __restrict__ batch,
                        unsigned* __restrict__ keys, float* __restrict__ cnt,
                        float* __restrict__ pacc) {
    int tid = threadIdx.x;
    int c = tid & 31;
    int i = blockIdx.x * 8 + (tid >> 5);
    float2 ss = bn_ss(st, g, be, c, INV_N);
    float z = y3[(size_t)i * 32 + c] * ss.x + ss.y;
    float px = pos[i * 3], py = pos[i * 3 + 1];
    int cx = min(max((int)floorf(px / 16.f), 0), 14);
    int cy = min(max((int)floorf(py / 12.f), 0), 14);
    int cl = batch[i] * 225 + cy * 15 + cx;
    atomicMax(&keys[cl * 32 + c], enc_f(z));
    if (c == 0) {
        atomicAdd(&cnt[cl], 1.f);
        atomicAdd(&pacc[cl * 3 + 0], px);
        atomicAdd(&pacc[cl * 3 + 1], py);
        atomicAdd(&pacc[cl * 3 + 2], pos[i * 3 + 2]);
    }
}

// ---------------- pool5 -----------------------------------------------------
__global__ void pool5_k(const float* __restrict__ y5, const float* __restrict__ st,
                        const float* __restrict__ g, const float* __restrict__ be,
                        const float* __restrict__ pacc, const float* __restrict__ cnt,
                        unsigned* __restrict__ keys5) {
    int idx = blockIdx.x * blockDim.x + threadIdx.x;   // 1800*128
    int i = idx / 128, c = idx % 128;
    float2 ss = bn_ss(st, g, be, c, INV_N2);
    float z = y5[idx] * ss.x + ss.y;
    float ic = 1.f / fmaxf(cnt[i], 1.f);
    float px = pacc[i * 3] * ic, py = pacc[i * 3 + 1] * ic;
    int cx = min(max((int)floorf(px / 60.f), 0), 3);
    int cy = min(max((int)floorf(py / 45.f), 0), 3);
    int b = i / 225;
    int cl = b * 16 + cy * 4 + cx;
    atomicMax(&keys5[cl * 128 + c], enc_f(z));
}

// ---------------- FC --------------------------------------------------------
__global__ void fc_k(const unsigned* __restrict__ keys5, const float* __restrict__ wfc,
                     float* __restrict__ out) {
    __shared__ float row[2048];
    int b = blockIdx.x;
    for (int k = threadIdx.x; k < 2048; k += 256) {
        unsigned kk = keys5[b * 2048 + k];
        row[k] = (kk == ENC_NEGINF) ? 0.f : dec_f(kk);
    }
    __syncthreads();
    int wave = threadIdx.x >> 6, lane = threadIdx.x & 63;
    int o = blockIdx.y * 4 + wave;
    if (o < 101) {
        float a = 0.f;
        for (int k = lane; k < 2048; k += 64)
            a += row[k] * wfc[k * 101 + o];
#pragma unroll
        for (int m = 32; m; m >>= 1) a += __shfl_xor(a, m);
        if (lane == 0) out[b * 101 + o] = a;
    }
}

extern "C" void kernel_launch(void* const* d_in, const int* in_sizes, int n_in,
                              void* d_out, int out_size, void* d_ws, size_t ws_size,
                              hipStream_t stream) {
    const float* x     = (const float*)d_in[0];
    const float* pos   = (const float*)d_in[1];
    const int*   batch = (const int*)d_in[2];
    const int*   e1    = (const int*)d_in[3];
    const int*   e2    = (const int*)d_in[4];
    const float* w_fc  = (const float*)d_in[40];
    auto WL = [&](int l) { return (const float*)d_in[5 + l * 7 + 0]; };
    auto WS = [&](int l) { return (const float*)d_in[5 + l * 7 + 1]; };
    auto WP = [&](int l) { return (const float*)d_in[5 + l * 7 + 3]; };
    auto BP = [&](int l) { return (const float*)d_in[5 + l * 7 + 4]; };
    auto G_ = [&](int l) { return (const float*)d_in[5 + l * 7 + 5]; };
    auto BE = [&](int l) { return (const float*)d_in[5 + l * 7 + 6]; };

    float* W = (float*)d_ws;
    size_t o = 0;
    float4* SHPf = (float4*)W;        o += 6400000;  // N*16 float4 (max, L1..L3)
    float2* CAPf = (float2*)(W + o);  o += 3200000;  // N*16 float2
    float*  Y1   = W + o;             o += 800000;
    float*  Y2   = W + o;             o += 800000;
    float*  Z1   = W + o;             o += 800000;
    float*  Y3   = W + o;             o += 3200000;
    float*  STATS = W + o;            o += 5 * 256;
    unsigned* KEYS3 = (unsigned*)(W + o); o += 57600;
    float*  CNT  = W + o;             o += 1800;
    float*  PACC = W + o;             o += 5400;
    float4* SHPc = (float4*)(W + o);  o += 460800;   // 1800*64 float4
    float2* CAPc = (float2*)(W + o);  o += 230400;
    float*  Y4   = W + o;             o += 57600;
    float*  Y5   = W + o;             o += 230400;
    unsigned* KEYS5 = (unsigned*)(W + o); o += 16384;

    hipLaunchKernelGGL(init_k, dim3(225), dim3(256), 0, stream,
                       STATS, KEYS3, CNT, PACC, KEYS5);

    // ---- L1 (1->8) fine ----
    hipLaunchKernelGGL((pass_a<1, 8, 0, false>), dim3(1563), dim3(256), 0, stream,
                       x, nullptr, nullptr, nullptr, nullptr, 0.f, nullptr,
                       WL(0), WS(0), WP(0), BP(0), pos, nullptr, nullptr,
                       SHPf, CAPf, nullptr, NN_FINE);
    hipLaunchKernelGGL((edge_pass<8, false>), dim3(1563), dim3(256), 0, stream,
                       SHPf, CAPf, e1, (float2*)Y1, NN_FINE);
    hipLaunchKernelGGL((stats_k<8>), dim3(64), dim3(256), 0, stream,
                       Y1, 800000, STATS + 0);

    // ---- L2 (8->8) fine, writes Z1=bn(Y1) ----
    hipLaunchKernelGGL((pass_a<8, 8, 1, false>), dim3(1563), dim3(256), 0, stream,
                       Y1, nullptr, STATS + 0, G_(0), BE(0), INV_N, nullptr,
                       WL(1), WS(1), WP(1), BP(1), pos, nullptr, nullptr,
                       SHPf, CAPf, Z1, NN_FINE);
    hipLaunchKernelGGL((edge_pass<8, false>), dim3(1563), dim3(256), 0, stream,
                       SHPf, CAPf, e1, (float2*)Y2, NN_FINE);
    hipLaunchKernelGGL((stats_k<8>), dim3(64), dim3(256), 0, stream,
                       Y2, 800000, STATS + 256);

    // ---- L3 (8->32) fine, f = bn(Y2)+Z1 ----
    hipLaunchKernelGGL((pass_a<8, 32, 2, false>), dim3(6250), dim3(256), 0, stream,
                       Y2, nullptr, STATS + 256, G_(1), BE(1), INV_N, Z1,
                       WL(2), WS(2), WP(2), BP(2), pos, nullptr, nullptr,
                       SHPf, CAPf, nullptr, NN_FINE);
    hipLaunchKernelGGL((edge_pass<32, false>), dim3(6250), dim3(256), 0, stream,
                       SHPf, CAPf, e1, (float2*)Y3, NN_FINE);
    hipLaunchKernelGGL((stats_k<32>), dim3(64), dim3(256), 0, stream,
                       Y3, 3200000, STATS + 512);

    // ---- pool3 ----
    hipLaunchKernelGGL(pool3_k, dim3(12500), dim3(256), 0, stream,
                       Y3, STATS + 512, G_(2), BE(2), pos, batch, KEYS3, CNT, PACC);

    // ---- L4 (32->32) coarse, f = dec(KEYS3) ----
    hipLaunchKernelGGL((pass_a<32, 32, 3, true>), dim3(113), dim3(256), 0, stream,
                       nullptr, KEYS3, nullptr, nullptr, nullptr, 0.f, nullptr,
                       WL(3), WS(3), WP(3), BP(3), nullptr, PACC, CNT,
                       SHPc, CAPc, nullptr, NN_COARSE);
    hipLaunchKernelGGL((edge_pass<32, true>), dim3(113), dim3(256), 0, stream,
                       SHPc, CAPc, e2, (float2*)Y4, NN_COARSE);
    hipLaunchKernelGGL((stats_k<32>), dim3(16), dim3(256), 0, stream,
                       Y4, 57600, STATS + 768);

    // ---- L5 (32->128) coarse, f = bn(Y4)+dec(KEYS3) ----
    hipLaunchKernelGGL((pass_a<32, 128, 4, true>), dim3(450), dim3(256), 0, stream,
                       Y4, KEYS3, STATS + 768, G_(3), BE(3), INV_N2, nullptr,
                       WL(4), WS(4), WP(4), BP(4), nullptr, PACC, CNT,
                       SHPc, CAPc, nullptr, NN_COARSE);
    hipLaunchKernelGGL((edge_pass<128, true>), dim3(450), dim3(256), 0, stream,
                       SHPc, CAPc, e2, (float2*)Y5, NN_COARSE);
    hipLaunchKernelGGL((stats_k<128>), dim3(32), dim3(256), 0, stream,
                       Y5, 230400, STATS + 1024);

    // ---- pool5 + FC ----
    hipLaunchKernelGGL(pool5_k, dim3(900), dim3(256), 0, stream,
                       Y5, STATS + 1024, G_(4), BE(4), PACC, CNT, KEYS5);
    hipLaunchKernelGGL(fc_k, dim3(8, 26), dim3(256), 0, stream,
                       KEYS5, w_fc, (float*)d_out);
}